// Round 1
// baseline (160.367 us; speedup 1.0000x reference)
//
#include <hip/hip_runtime.h>
#include <hip/hip_bf16.h>
#include <math.h>

// Problem constants
#define BB 512      // batch (edges)
#define NN 4096     // nodes
#define LL 128      // feature dim
#define IN_DIM 385  // 3*L + ND

// ---------------------------------------------------------------------------
// Kernel A: per-(edge,side) MLP message + atomic segment accumulation.
// grid = 2*B blocks (task = edge*2 + which), block = 128 threads.
// which==0 -> src message (weights src_*), accumulates at node s
// which==1 -> tar message (weights tar_*), accumulates at node t
// in = [mem[node], mem[other], delta_t[e, node, :], x[e, node]]
// ---------------------------------------------------------------------------
__global__ __launch_bounds__(LL) void edge_msg_kernel(
    const float* __restrict__ x,        // (B, N, 1)
    const float* __restrict__ memory,   // (N, L)
    const float* __restrict__ delta_t,  // (B, N, L)
    const float* __restrict__ src_w1, const float* __restrict__ src_b1,
    const float* __restrict__ src_w2, const float* __restrict__ src_b2,
    const float* __restrict__ tar_w1, const float* __restrict__ tar_b1,
    const float* __restrict__ tar_w2, const float* __restrict__ tar_b2,
    const int* __restrict__ source,     // (B,1) int32
    const int* __restrict__ target,     // (B,1) int32
    float* __restrict__ msg_sum,        // (N, L) accum
    float* __restrict__ cnt)            // (N,) accum
{
    const int task  = blockIdx.x;
    const int e     = task >> 1;
    const int which = task & 1;
    const int tid   = threadIdx.x;

    const int s = source[e];
    const int t = target[e];
    const int node  = which ? t : s;
    const int other = which ? s : t;

    const float* w1 = which ? tar_w1 : src_w1;
    const float* b1 = which ? tar_b1 : src_b1;
    const float* w2 = which ? tar_w2 : src_w2;
    const float* b2 = which ? tar_b2 : src_b2;

    __shared__ float in_s[IN_DIM];
    __shared__ float h1_s[LL];

    // Stage the 385-element input vector into LDS.
    in_s[tid]           = memory[(size_t)node * LL + tid];
    in_s[LL + tid]      = memory[(size_t)other * LL + tid];
    in_s[2 * LL + tid]  = delta_t[(size_t)e * NN * LL + (size_t)node * LL + tid];
    if (tid == 0)
        in_s[3 * LL] = x[(size_t)e * NN + node];   // ND == 1
    __syncthreads();

    // Layer 1: h1[j] = relu(b1[j] + sum_k w1[j,k] * in[k]),  w1 is (L, IN)
    {
        float acc = b1[tid];
        const float* wrow = w1 + (size_t)tid * IN_DIM;
        #pragma unroll 8
        for (int k = 0; k < IN_DIM; ++k)
            acc = fmaf(wrow[k], in_s[k], acc);
        h1_s[tid] = fmaxf(acc, 0.0f);
    }
    __syncthreads();

    // Layer 2: msg[j] = b2[j] + sum_k w2[j,k] * h1[k],  w2 is (L, L)
    {
        float acc = b2[tid];
        const float* wrow = w2 + (size_t)tid * LL;
        #pragma unroll 8
        for (int k = 0; k < LL; ++k)
            acc = fmaf(wrow[k], h1_s[k], acc);
        atomicAdd(&msg_sum[(size_t)node * LL + tid], acc);
    }
    if (tid == 0)
        atomicAdd(&cnt[node], 1.0f);
}

// ---------------------------------------------------------------------------
// Kernel B: per-node GRU update (or passthrough copy for unseen nodes).
// grid = N blocks, block = 128 threads.
// ---------------------------------------------------------------------------
__global__ __launch_bounds__(LL) void gru_kernel(
    const float* __restrict__ memory,   // (N, L)
    const float* __restrict__ msg_sum,  // (N, L)
    const float* __restrict__ cnt,      // (N,)
    const float* __restrict__ wih,      // (3L, L)
    const float* __restrict__ whh,      // (3L, L)
    const float* __restrict__ bih,      // (3L,)
    const float* __restrict__ bhh,      // (3L,)
    float* __restrict__ out)            // (N, L)
{
    const int n   = blockIdx.x;
    const int tid = threadIdx.x;

    const float h = memory[(size_t)n * LL + tid];
    const float c = cnt[n];

    if (c <= 0.0f) {           // unseen node: passthrough (uniform per block)
        out[(size_t)n * LL + tid] = h;
        return;
    }

    __shared__ float agg_s[LL];
    __shared__ float h_s[LL];
    agg_s[tid] = msg_sum[(size_t)n * LL + tid] / c;   // c >= 1 here
    h_s[tid]   = h;
    __syncthreads();

    float ir = bih[tid], iz = bih[LL + tid], inn = bih[2 * LL + tid];
    float hr = bhh[tid], hz = bhh[LL + tid], hn  = bhh[2 * LL + tid];

    const float* wr = wih + (size_t)tid * LL;
    const float* wz = wih + (size_t)(LL + tid) * LL;
    const float* wn = wih + (size_t)(2 * LL + tid) * LL;
    const float* vr = whh + (size_t)tid * LL;
    const float* vz = whh + (size_t)(LL + tid) * LL;
    const float* vn = whh + (size_t)(2 * LL + tid) * LL;

    #pragma unroll 4
    for (int k = 0; k < LL; ++k) {
        const float a  = agg_s[k];
        const float hh = h_s[k];
        ir = fmaf(wr[k], a, ir);
        iz = fmaf(wz[k], a, iz);
        inn = fmaf(wn[k], a, inn);
        hr = fmaf(vr[k], hh, hr);
        hz = fmaf(vz[k], hh, hz);
        hn = fmaf(vn[k], hh, hn);
    }

    const float r = 1.0f / (1.0f + __expf(-(ir + hr)));
    const float z = 1.0f / (1.0f + __expf(-(iz + hz)));
    const float nn = tanhf(inn + r * hn);

    out[(size_t)n * LL + tid] = (1.0f - z) * nn + z * h;
}

// ---------------------------------------------------------------------------
extern "C" void kernel_launch(void* const* d_in, const int* in_sizes, int n_in,
                              void* d_out, int out_size, void* d_ws, size_t ws_size,
                              hipStream_t stream) {
    const float* x        = (const float*)d_in[0];
    const float* memory   = (const float*)d_in[1];
    const float* delta_t  = (const float*)d_in[2];
    const float* src_w1   = (const float*)d_in[3];
    const float* src_b1   = (const float*)d_in[4];
    const float* src_w2   = (const float*)d_in[5];
    const float* src_b2   = (const float*)d_in[6];
    const float* tar_w1   = (const float*)d_in[7];
    const float* tar_b1   = (const float*)d_in[8];
    const float* tar_w2   = (const float*)d_in[9];
    const float* tar_b2   = (const float*)d_in[10];
    const float* gru_wih  = (const float*)d_in[11];
    const float* gru_whh  = (const float*)d_in[12];
    const float* gru_bih  = (const float*)d_in[13];
    const float* gru_bhh  = (const float*)d_in[14];
    const int*   source   = (const int*)d_in[15];
    const int*   target   = (const int*)d_in[16];

    float* out = (float*)d_out;

    // Workspace: msg_sum (N*L f32) then cnt (N f32)
    float* msg_sum = (float*)d_ws;
    float* cnt     = msg_sum + (size_t)NN * LL;
    const size_t zero_bytes = ((size_t)NN * LL + NN) * sizeof(float);
    hipMemsetAsync(d_ws, 0, zero_bytes, stream);

    edge_msg_kernel<<<2 * BB, LL, 0, stream>>>(
        x, memory, delta_t,
        src_w1, src_b1, src_w2, src_b2,
        tar_w1, tar_b1, tar_w2, tar_b2,
        source, target, msg_sum, cnt);

    gru_kernel<<<NN, LL, 0, stream>>>(
        memory, msg_sum, cnt,
        gru_wih, gru_whh, gru_bih, gru_bhh, out);
}

// Round 2
// 63.101 us; speedup vs baseline: 2.5414x; 2.5414x over previous
//
#include <hip/hip_runtime.h>
#include <math.h>

// Problem constants
#define BB 512      // batch (edges)
#define NN 4096     // nodes
#define LL 128      // feature dim
#define IN_DIM 385  // 3*L + ND

// ---------------------------------------------------------------------------
// Workspace layout (float offsets)
// ---------------------------------------------------------------------------
#define OFF_MSG   0                          // msg_sum (N*L)
#define OFF_CNT   (OFF_MSG + NN * LL)        // cnt (N)
#define OFF_COUNT (OFF_CNT + NN)             // seen_count (1 int) + pad
#define OFF_LIST  (OFF_COUNT + 4)            // seen list (1024 ints)
#define OFF_W1TS  (OFF_LIST + 1024)          // src_w1^T (IN_DIM x L)
#define OFF_W1TT  (OFF_W1TS + IN_DIM * LL)   // tar_w1^T
#define OFF_W2TS  (OFF_W1TT + IN_DIM * LL)   // src_w2^T (L x L)
#define OFF_W2TT  (OFF_W2TS + LL * LL)       // tar_w2^T
#define OFF_WIHT  (OFF_W2TT + LL * LL)       // gru_wih^T (L x 3L)
#define OFF_WHHT  (OFF_WIHT + 3 * LL * LL)   // gru_whh^T (L x 3L)
#define WS_FLOATS (OFF_WHHT + 3 * LL * LL)   // ~759K floats ~ 3.0 MB

// ---------------------------------------------------------------------------
// Prep kernel: fuses {memory->out passthrough copy, msg_sum/cnt/count zeroing,
// all 6 weight transposes}. Runs every launch (deterministic).
// ---------------------------------------------------------------------------
__global__ __launch_bounds__(256) void prep_kernel(
    const float* __restrict__ memory,
    const float* __restrict__ sw1, const float* __restrict__ tw1,
    const float* __restrict__ sw2, const float* __restrict__ tw2,
    const float* __restrict__ wih, const float* __restrict__ whh,
    float* __restrict__ ws, float* __restrict__ out)
{
    const int i = blockIdx.x * blockDim.x + threadIdx.x;
    const int stride = gridDim.x * blockDim.x;

    // passthrough copy + zero accumulators
    for (int idx = i; idx < NN * LL; idx += stride) {
        out[idx] = memory[idx];
        ws[OFF_MSG + idx] = 0.0f;
    }
    for (int idx = i; idx < NN; idx += stride)
        ws[OFF_CNT + idx] = 0.0f;
    if (i == 0)
        ((int*)ws)[OFF_COUNT] = 0;

    // transpose (L, IN) -> (IN, L) for both MLP layer-1 weights
    for (int idx = i; idx < IN_DIM * LL; idx += stride) {
        const int j = idx / IN_DIM;          // output row
        const int k = idx - j * IN_DIM;      // input col
        ws[OFF_W1TS + k * LL + j] = sw1[idx];
        ws[OFF_W1TT + k * LL + j] = tw1[idx];
    }
    // transpose (L, L) for layer-2 weights
    for (int idx = i; idx < LL * LL; idx += stride) {
        const int j = idx >> 7, k = idx & 127;
        ws[OFF_W2TS + k * LL + j] = sw2[idx];
        ws[OFF_W2TT + k * LL + j] = tw2[idx];
    }
    // transpose (3L, L) -> (L, 3L) for GRU weights
    for (int idx = i; idx < 3 * LL * LL; idx += stride) {
        const int r = idx >> 7, c = idx & 127;
        ws[OFF_WIHT + c * (3 * LL) + r] = wih[idx];
        ws[OFF_WHHT + c * (3 * LL) + r] = whh[idx];
    }
}

// ---------------------------------------------------------------------------
// Edge-message kernel: one block = one side (src/tar) of TWO edges.
// 256 threads = 2 k-split groups x 128 output features. Coalesced transposed
// weight loads, LDS-broadcast inputs, atomic segment accumulation, and
// first-toucher compaction of the seen-node list.
// ---------------------------------------------------------------------------
__global__ __launch_bounds__(256) void edge_msg_kernel(
    const float* __restrict__ x,        // (B, N, 1)
    const float* __restrict__ memory,   // (N, L)
    const float* __restrict__ delta_t,  // (B, N, L)
    const float* __restrict__ sb1, const float* __restrict__ sb2,
    const float* __restrict__ tb1, const float* __restrict__ tb2,
    const int* __restrict__ source, const int* __restrict__ target,
    float* __restrict__ ws)
{
    const int side = blockIdx.x & 1;     // 0 = src message, 1 = tar message
    const int pair = blockIdx.x >> 1;
    const int tid  = threadIdx.x;
    const int g    = tid >> 7;           // k-split group (0/1)
    const int j    = tid & 127;          // output feature

    __shared__ float in2[IN_DIM][2];     // staged inputs for both edges
    __shared__ float part1[2][2][LL];    // [g][e][j] layer-1 partials
    __shared__ float h1[LL][2];          // [k][e] layer-1 activations
    __shared__ float part2[2][2][LL];    // [g][e][j] layer-2 partials
    __shared__ int   node_sh[2];

    const float* w1T = ws + (side ? OFF_W1TT : OFF_W1TS);
    const float* w2T = ws + (side ? OFF_W2TT : OFF_W2TS);
    const float* b1  = side ? tb1 : sb1;
    const float* b2  = side ? tb2 : sb2;

    // Stage both edges' 385-element input vectors.
    #pragma unroll
    for (int e = 0; e < 2; ++e) {
        const int eg = pair * 2 + e;
        const int s = source[eg], t = target[eg];
        const int node  = side ? t : s;
        const int other = side ? s : t;
        if (tid == 0) node_sh[e] = node;
        for (int idx = tid; idx < IN_DIM; idx += 256) {
            float v;
            if (idx < LL)            v = memory[node * LL + idx];
            else if (idx < 2 * LL)   v = memory[other * LL + (idx - LL)];
            else if (idx < 3 * LL)   v = delta_t[((size_t)eg * NN + node) * LL + (idx - 2 * LL)];
            else                     v = x[(size_t)eg * NN + node];
            in2[idx][e] = v;
        }
    }
    __syncthreads();

    // Layer 1 (k-split: g0 -> [0,193), g1 -> [193,385))
    {
        const int k0 = g ? 193 : 0;
        const int k1 = g ? IN_DIM : 193;
        float a0 = 0.0f, a1 = 0.0f;
        #pragma unroll 4
        for (int k = k0; k < k1; ++k) {
            const float w = w1T[k * LL + j];
            a0 = fmaf(w, in2[k][0], a0);
            a1 = fmaf(w, in2[k][1], a1);
        }
        part1[g][0][j] = a0;
        part1[g][1][j] = a1;
    }
    __syncthreads();

    // Combine partials + bias + relu; thread (g,j) finishes edge e=g.
    {
        const float v = part1[0][g][j] + part1[1][g][j] + b1[j];
        h1[j][g] = fmaxf(v, 0.0f);
    }
    __syncthreads();

    // Layer 2 (k-split halves of 128)
    {
        const int m0 = g * 64, m1 = m0 + 64;
        float c0 = 0.0f, c1 = 0.0f;
        #pragma unroll 4
        for (int k = m0; k < m1; ++k) {
            const float w = w2T[k * LL + j];
            c0 = fmaf(w, h1[k][0], c0);
            c1 = fmaf(w, h1[k][1], c1);
        }
        part2[g][0][j] = c0;
        part2[g][1][j] = c1;
    }
    __syncthreads();

    // Final message for edge e=g; atomic segment-sum.
    {
        const int e = g;
        const float msgv = part2[0][e][j] + part2[1][e][j] + b2[j];
        atomicAdd(ws + OFF_MSG + node_sh[e] * LL + j, msgv);
    }
    // Count + first-toucher list append (one per (edge,side) task).
    if (tid < 2) {
        const int node = node_sh[tid];
        const float old = atomicAdd(ws + OFF_CNT + node, 1.0f);
        if (old == 0.0f) {
            const int pos = atomicAdd((int*)ws + OFF_COUNT, 1);
            ((int*)ws)[OFF_LIST + pos] = node;
        }
    }
}

// ---------------------------------------------------------------------------
// GRU kernel over the COMPACT seen list only. 4 nodes per block; transposed
// coalesced weight loads reused across the 4 nodes; agg/h staged in LDS
// transposed so each k-iteration is two broadcast float4 reads.
// ---------------------------------------------------------------------------
__global__ __launch_bounds__(128) void gru_kernel(
    const float* __restrict__ memory,
    const float* __restrict__ bih, const float* __restrict__ bhh,
    float* __restrict__ ws, float* __restrict__ out)
{
    const int tid = threadIdx.x;
    const int scount = ((const int*)ws)[OFF_COUNT];
    const int base = blockIdx.x * 4;
    if (base >= scount) return;
    const int nact = min(4, scount - base);

    __shared__ float ah[LL][8];   // [k][0..3]=agg, [k][4..7]=h
    __shared__ int nodes[4];

    #pragma unroll
    for (int gi = 0; gi < 4; ++gi) {
        if (gi < nact) {
            const int node = ((const int*)ws)[OFF_LIST + base + gi];
            if (tid == 0) nodes[gi] = node;
            const float c = ws[OFF_CNT + node];
            ah[tid][gi]     = ws[OFF_MSG + node * LL + tid] / c;
            ah[tid][4 + gi] = memory[node * LL + tid];
        } else {
            ah[tid][gi] = 0.0f;
            ah[tid][4 + gi] = 0.0f;
        }
    }
    __syncthreads();

    const float* wihT = ws + OFF_WIHT;
    const float* whhT = ws + OFF_WHHT;

    float accIR[4] = {0, 0, 0, 0}, accIZ[4] = {0, 0, 0, 0}, accIN[4] = {0, 0, 0, 0};
    float accHR[4] = {0, 0, 0, 0}, accHZ[4] = {0, 0, 0, 0}, accHN[4] = {0, 0, 0, 0};

    #pragma unroll 2
    for (int k = 0; k < LL; ++k) {
        const float wr = wihT[k * 384 + tid];
        const float wz = wihT[k * 384 + 128 + tid];
        const float wn = wihT[k * 384 + 256 + tid];
        const float vr = whhT[k * 384 + tid];
        const float vz = whhT[k * 384 + 128 + tid];
        const float vn = whhT[k * 384 + 256 + tid];
        const float4 a4 = *(const float4*)&ah[k][0];
        const float4 h4 = *(const float4*)&ah[k][4];
        const float av[4] = {a4.x, a4.y, a4.z, a4.w};
        const float hv[4] = {h4.x, h4.y, h4.z, h4.w};
        #pragma unroll
        for (int gi = 0; gi < 4; ++gi) {
            accIR[gi] = fmaf(wr, av[gi], accIR[gi]);
            accIZ[gi] = fmaf(wz, av[gi], accIZ[gi]);
            accIN[gi] = fmaf(wn, av[gi], accIN[gi]);
            accHR[gi] = fmaf(vr, hv[gi], accHR[gi]);
            accHZ[gi] = fmaf(vz, hv[gi], accHZ[gi]);
            accHN[gi] = fmaf(vn, hv[gi], accHN[gi]);
        }
    }

    const float br = bih[tid], bz = bih[128 + tid], bn = bih[256 + tid];
    const float cr = bhh[tid], cz = bhh[128 + tid], cn = bhh[256 + tid];

    for (int gi = 0; gi < nact; ++gi) {
        const int node = nodes[gi];
        const float r = 1.0f / (1.0f + __expf(-(accIR[gi] + br + accHR[gi] + cr)));
        const float z = 1.0f / (1.0f + __expf(-(accIZ[gi] + bz + accHZ[gi] + cz)));
        const float n = tanhf(accIN[gi] + bn + r * (accHN[gi] + cn));
        const float h = ah[tid][4 + gi];
        out[node * LL + tid] = (1.0f - z) * n + z * h;
    }
}

// ---------------------------------------------------------------------------
extern "C" void kernel_launch(void* const* d_in, const int* in_sizes, int n_in,
                              void* d_out, int out_size, void* d_ws, size_t ws_size,
                              hipStream_t stream) {
    const float* x        = (const float*)d_in[0];
    const float* memory   = (const float*)d_in[1];
    const float* delta_t  = (const float*)d_in[2];
    const float* src_w1   = (const float*)d_in[3];
    const float* src_b1   = (const float*)d_in[4];
    const float* src_w2   = (const float*)d_in[5];
    const float* src_b2   = (const float*)d_in[6];
    const float* tar_w1   = (const float*)d_in[7];
    const float* tar_b1   = (const float*)d_in[8];
    const float* tar_w2   = (const float*)d_in[9];
    const float* tar_b2   = (const float*)d_in[10];
    const float* gru_wih  = (const float*)d_in[11];
    const float* gru_whh  = (const float*)d_in[12];
    const float* gru_bih  = (const float*)d_in[13];
    const float* gru_bhh  = (const float*)d_in[14];
    const int*   source   = (const int*)d_in[15];
    const int*   target   = (const int*)d_in[16];

    float* out = (float*)d_out;
    float* ws  = (float*)d_ws;

    // 1) prep: copy-through + zero + transposes (fuses old memset)
    prep_kernel<<<512, 256, 0, stream>>>(
        memory, src_w1, tar_w1, src_w2, tar_w2, gru_wih, gru_whh, ws, out);

    // 2) edge messages: 2 sides x 256 edge-pairs = 512 blocks
    edge_msg_kernel<<<512, 256, 0, stream>>>(
        x, memory, delta_t, src_b1, src_b2, tar_b1, tar_b2,
        source, target, ws);

    // 3) GRU over compact seen list: 256 blocks x 4 nodes = 1024 slots max
    gru_kernel<<<256, 128, 0, stream>>>(
        memory, gru_bih, gru_bhh, ws, out);
}

// Round 3
// 59.889 us; speedup vs baseline: 2.6777x; 1.0536x over previous
//
#include <hip/hip_runtime.h>
#include <math.h>

// Problem constants
#define BB 512      // batch (edges)
#define NN 4096     // nodes
#define LL 128      // feature dim
#define IN_DIM 385  // 3*L + ND
#define EPB 4       // edges per block (edge kernel)
#define GPB 8       // nodes per block (gru kernel)

// ---------------------------------------------------------------------------
// Workspace layout (float offsets)
// ---------------------------------------------------------------------------
#define OFF_MSG   0                          // msg_sum (N*L)
#define OFF_CNT   (OFF_MSG + NN * LL)        // cnt (N)
#define OFF_COUNT (OFF_CNT + NN)             // seen_count (1 int) + pad
#define OFF_LIST  (OFF_COUNT + 4)            // seen list (1024 ints)
#define OFF_W1TS  (OFF_LIST + 1024)          // src_w1^T (IN_DIM x L), [k][j]
#define OFF_W1TT  (OFF_W1TS + IN_DIM * LL)   // tar_w1^T
#define OFF_W2TS  (OFF_W1TT + IN_DIM * LL)   // src_w2^T (L x L)
#define OFF_W2TT  (OFF_W2TS + LL * LL)       // tar_w2^T
#define OFF_WIHT  (OFF_W2TT + LL * LL)       // gru_wih^T (L x 3L), [k][row]
#define OFF_WHHT  (OFF_WIHT + 3 * LL * LL)   // gru_whh^T (L x 3L)

// ---------------------------------------------------------------------------
// Prep: passthrough copy (float4), zero accumulators, weight transposes with
// COALESCED WRITES (iterate output index; reads are scattered but L2-cached).
// ---------------------------------------------------------------------------
__global__ __launch_bounds__(256) void prep_kernel(
    const float* __restrict__ memory,
    const float* __restrict__ sw1, const float* __restrict__ tw1,
    const float* __restrict__ sw2, const float* __restrict__ tw2,
    const float* __restrict__ wih, const float* __restrict__ whh,
    float* __restrict__ ws, float* __restrict__ out)
{
    const int i = blockIdx.x * 256 + threadIdx.x;
    const int stride = gridDim.x * 256;

    // passthrough copy + zero msg_sum, vectorized
    float4* out4 = (float4*)out;
    const float4* mem4 = (const float4*)memory;
    float4* msg4 = (float4*)(ws + OFF_MSG);
    const float4 z4 = make_float4(0.f, 0.f, 0.f, 0.f);
    for (int idx = i; idx < NN * LL / 4; idx += stride) {
        out4[idx] = mem4[idx];
        msg4[idx] = z4;
    }
    for (int idx = i; idx < NN; idx += stride)
        ws[OFF_CNT + idx] = 0.0f;
    if (i == 0)
        ((int*)ws)[OFF_COUNT] = 0;

    // w1: (L, IN) -> w1T[k*L + j] ; output-idx iteration => coalesced writes
    for (int idx = i; idx < IN_DIM * LL; idx += stride) {
        const int k = idx >> 7, j = idx & 127;
        ws[OFF_W1TS + idx] = sw1[j * IN_DIM + k];
        ws[OFF_W1TT + idx] = tw1[j * IN_DIM + k];
    }
    // w2: (L, L) -> w2T[k*L + j]
    for (int idx = i; idx < LL * LL; idx += stride) {
        const int k = idx >> 7, j = idx & 127;
        ws[OFF_W2TS + idx] = sw2[j * LL + k];
        ws[OFF_W2TT + idx] = tw2[j * LL + k];
    }
    // gru: (3L, L) -> wT[k*3L + row]
    for (int idx = i; idx < 3 * LL * LL; idx += stride) {
        const int k = idx / 384, r = idx - k * 384;
        ws[OFF_WIHT + idx] = wih[r * LL + k];
        ws[OFF_WHHT + idx] = whh[r * LL + k];
    }
}

// ---------------------------------------------------------------------------
// Edge messages: one block = one side of EPB edges. 256 threads =
// 2 k-groups x 128 output features. Transposed weights (coalesced), inputs
// staged in LDS and read as broadcast float4 across the EPB edges.
// ---------------------------------------------------------------------------
__global__ __launch_bounds__(256) void edge_msg_kernel(
    const float* __restrict__ x,        // (B, N, 1)
    const float* __restrict__ memory,   // (N, L)
    const float* __restrict__ delta_t,  // (B, N, L)
    const float* __restrict__ sb1, const float* __restrict__ sb2,
    const float* __restrict__ tb1, const float* __restrict__ tb2,
    const int* __restrict__ source, const int* __restrict__ target,
    float* __restrict__ ws)
{
    const int side  = blockIdx.x & 1;
    const int chunk = blockIdx.x >> 1;       // 0 .. BB/EPB-1
    const int tid   = threadIdx.x;
    const int g     = tid >> 7;              // k-split group
    const int j     = tid & 127;             // output feature

    __shared__ float in2[IN_DIM][EPB];       // [k][e], float4-readable
    __shared__ float h1[LL][EPB];            // [k][e]
    __shared__ float part1[2][EPB][LL];
    __shared__ float part2[2][EPB][LL];
    __shared__ int   node_sh[EPB];

    const float* w1T = ws + (side ? OFF_W1TT : OFF_W1TS);
    const float* w2T = ws + (side ? OFF_W2TT : OFF_W2TS);
    const float* b1  = side ? tb1 : sb1;
    const float* b2  = side ? tb2 : sb2;

    // Stage EPB edges' input vectors.
    #pragma unroll
    for (int e = 0; e < EPB; ++e) {
        const int eg = chunk * EPB + e;
        const int s = source[eg], t = target[eg];
        const int node  = side ? t : s;
        const int other = side ? s : t;
        if (tid == 0) node_sh[e] = node;
        for (int idx = tid; idx < IN_DIM; idx += 256) {
            float v;
            if (idx < LL)            v = memory[node * LL + idx];
            else if (idx < 2 * LL)   v = memory[other * LL + (idx - LL)];
            else if (idx < 3 * LL)   v = delta_t[((size_t)eg * NN + node) * LL + (idx - 2 * LL)];
            else                     v = x[(size_t)eg * NN + node];
            in2[idx][e] = v;
        }
    }
    __syncthreads();

    // Layer 1 (k-split: g0 -> [0,193), g1 -> [193,385))
    {
        const int k0 = g ? 193 : 0;
        const int k1 = g ? IN_DIM : 193;
        float a[EPB] = {0.f, 0.f, 0.f, 0.f};
        #pragma unroll 4
        for (int k = k0; k < k1; ++k) {
            const float w = w1T[k * LL + j];
            const float4 iv = *(const float4*)&in2[k][0];   // broadcast
            a[0] = fmaf(w, iv.x, a[0]);
            a[1] = fmaf(w, iv.y, a[1]);
            a[2] = fmaf(w, iv.z, a[2]);
            a[3] = fmaf(w, iv.w, a[3]);
        }
        #pragma unroll
        for (int e = 0; e < EPB; ++e) part1[g][e][j] = a[e];
    }
    __syncthreads();

    // Combine + bias + relu; thread (g,j) finishes edges e = 2g, 2g+1.
    #pragma unroll
    for (int q = 0; q < EPB / 2; ++q) {
        const int e = g * (EPB / 2) + q;
        h1[j][e] = fmaxf(part1[0][e][j] + part1[1][e][j] + b1[j], 0.0f);
    }
    __syncthreads();

    // Layer 2 (k-split halves of 128)
    {
        const int k0 = g * 64, k1 = k0 + 64;
        float a[EPB] = {0.f, 0.f, 0.f, 0.f};
        #pragma unroll 4
        for (int k = k0; k < k1; ++k) {
            const float w = w2T[k * LL + j];
            const float4 hv = *(const float4*)&h1[k][0];    // broadcast
            a[0] = fmaf(w, hv.x, a[0]);
            a[1] = fmaf(w, hv.y, a[1]);
            a[2] = fmaf(w, hv.z, a[2]);
            a[3] = fmaf(w, hv.w, a[3]);
        }
        #pragma unroll
        for (int e = 0; e < EPB; ++e) part2[g][e][j] = a[e];
    }
    __syncthreads();

    // Final messages; atomic segment-sum.
    #pragma unroll
    for (int q = 0; q < EPB / 2; ++q) {
        const int e = g * (EPB / 2) + q;
        const float m = part2[0][e][j] + part2[1][e][j] + b2[j];
        atomicAdd(ws + OFF_MSG + node_sh[e] * LL + j, m);
    }
    // Count + first-toucher compaction.
    if (tid < EPB) {
        const int node = node_sh[tid];
        const float old = atomicAdd(ws + OFF_CNT + node, 1.0f);
        if (old == 0.0f) {
            const int pos = atomicAdd((int*)ws + OFF_COUNT, 1);
            ((int*)ws)[OFF_LIST + pos] = node;
        }
    }
}

// ---------------------------------------------------------------------------
// GRU over the compact seen list. GPB nodes/block, 256 threads:
// group 0 computes the 3 wih gates against agg, group 1 the 3 whh gates
// against h (gate-split: no cross-group partial reduction needed).
// ---------------------------------------------------------------------------
__global__ __launch_bounds__(256) void gru_kernel(
    const float* __restrict__ memory,
    const float* __restrict__ bih, const float* __restrict__ bhh,
    float* __restrict__ ws, float* __restrict__ out)
{
    const int tid = threadIdx.x;
    const int g = tid >> 7, j = tid & 127;
    const int scount = ((const int*)ws)[OFF_COUNT];
    const int base = blockIdx.x * GPB;
    if (base >= scount) return;
    const int nact = min(GPB, scount - base);

    __shared__ float ah[LL][2 * GPB + 1];    // [k][slot] 0..7=agg, 8..15=h; pad 17
    __shared__ float gates[6][GPB][LL];      // [gate][node][j]
    __shared__ int   nodes_sh[GPB];

    if (tid < GPB)
        nodes_sh[tid] = (base + tid < scount)
                        ? ((const int*)ws)[OFF_LIST + base + tid] : -1;
    __syncthreads();

    // Stage agg (g=0) and h (g=1) for all GPB nodes, coalesced over j.
    #pragma unroll
    for (int gi = 0; gi < GPB; ++gi) {
        const int node = nodes_sh[gi];
        if (g == 0) {
            float v = 0.0f;
            if (node >= 0) {
                const float c = ws[OFF_CNT + node];
                v = ws[OFF_MSG + node * LL + j] / c;
            }
            ah[j][gi] = v;
        } else {
            ah[j][GPB + gi] = (node >= 0) ? memory[node * LL + j] : 0.0f;
        }
    }
    __syncthreads();

    // 3 gate matvecs for this group's operand, 8 nodes amortizing each load.
    const float* wT = ws + (g ? OFF_WHHT : OFF_WIHT);
    float a0[GPB] = {}, a1[GPB] = {}, a2[GPB] = {};
    #pragma unroll 2
    for (int k = 0; k < LL; ++k) {
        const float w0 = wT[k * 384 + j];
        const float w1 = wT[k * 384 + 128 + j];
        const float w2 = wT[k * 384 + 256 + j];
        #pragma unroll
        for (int gi = 0; gi < GPB; ++gi) {
            const float v = ah[k][g * GPB + gi];   // broadcast
            a0[gi] = fmaf(w0, v, a0[gi]);
            a1[gi] = fmaf(w1, v, a1[gi]);
            a2[gi] = fmaf(w2, v, a2[gi]);
        }
    }
    #pragma unroll
    for (int gi = 0; gi < GPB; ++gi) {
        gates[g * 3 + 0][gi][j] = a0[gi];
        gates[g * 3 + 1][gi][j] = a1[gi];
        gates[g * 3 + 2][gi][j] = a2[gi];
    }
    __syncthreads();

    // Finalize: 4 outputs per thread, coalesced.
    const int total = nact * LL;
    for (int o = tid; o < total; o += 256) {
        const int gi = o >> 7, jj = o & 127;
        const int node = nodes_sh[gi];
        const float ir = gates[0][gi][jj] + bih[jj];
        const float iz = gates[1][gi][jj] + bih[LL + jj];
        const float inn = gates[2][gi][jj] + bih[2 * LL + jj];
        const float hr = gates[3][gi][jj] + bhh[jj];
        const float hz = gates[4][gi][jj] + bhh[LL + jj];
        const float hn = gates[5][gi][jj] + bhh[2 * LL + jj];
        const float r = 1.0f / (1.0f + __expf(-(ir + hr)));
        const float z = 1.0f / (1.0f + __expf(-(iz + hz)));
        const float n = tanhf(inn + r * hn);
        const float h = ah[jj][GPB + gi];
        out[node * LL + jj] = (1.0f - z) * n + z * h;
    }
}

// ---------------------------------------------------------------------------
extern "C" void kernel_launch(void* const* d_in, const int* in_sizes, int n_in,
                              void* d_out, int out_size, void* d_ws, size_t ws_size,
                              hipStream_t stream) {
    const float* x        = (const float*)d_in[0];
    const float* memory   = (const float*)d_in[1];
    const float* delta_t  = (const float*)d_in[2];
    const float* src_w1   = (const float*)d_in[3];
    const float* src_b1   = (const float*)d_in[4];
    const float* src_w2   = (const float*)d_in[5];
    const float* src_b2   = (const float*)d_in[6];
    const float* tar_w1   = (const float*)d_in[7];
    const float* tar_b1   = (const float*)d_in[8];
    const float* tar_w2   = (const float*)d_in[9];
    const float* tar_b2   = (const float*)d_in[10];
    const float* gru_wih  = (const float*)d_in[11];
    const float* gru_whh  = (const float*)d_in[12];
    const float* gru_bih  = (const float*)d_in[13];
    const float* gru_bhh  = (const float*)d_in[14];
    const int*   source   = (const int*)d_in[15];
    const int*   target   = (const int*)d_in[16];

    float* out = (float*)d_out;
    float* ws  = (float*)d_ws;

    // 1) prep: copy-through + zero + coalesced-write transposes
    prep_kernel<<<512, 256, 0, stream>>>(
        memory, src_w1, tar_w1, src_w2, tar_w2, gru_wih, gru_whh, ws, out);

    // 2) edge messages: 2 sides x (512/EPB) chunks = 256 blocks
    edge_msg_kernel<<<2 * (BB / EPB), 256, 0, stream>>>(
        x, memory, delta_t, src_b1, src_b2, tar_b1, tar_b2,
        source, target, ws);

    // 3) GRU over compact seen list: 1024/GPB = 128 blocks
    gru_kernel<<<1024 / GPB, 256, 0, stream>>>(
        memory, gru_bih, gru_bhh, ws, out);
}